// Round 15
// baseline (332.589 us; speedup 1.0000x reference)
//
#include <hip/hip_runtime.h>
#include <hip/hip_fp16.h>
#include <math.h>

#define NN 100000
#define EE 3200000
#define ET (EE + NN)
#define BKW 128                       // dsts per bucket
#define NBK ((NN + BKW - 1) / BKW)    // 782 buckets
#define BCAP 5120                     // per-bucket capacity
#define EPB 8192                      // edges per p1 block (two-phase)
#define NB_P1 ((EE + EPB - 1) / EPB)  // 391
#define NB_G 391                      // gemm blocks: 391*256 = 100096 >= NN

typedef float v2f __attribute__((ext_vector_type(2)));
typedef float v4f __attribute__((ext_vector_type(4)));
typedef _Float16 v8h __attribute__((ext_vector_type(8)));

__device__ __forceinline__ float lrelu(float v) { return fmaxf(v, 0.2f * v); }

__device__ __forceinline__ unsigned char to_fp8(float v) {
  return (unsigned char)(__builtin_amdgcn_cvt_pk_fp8_f32(v, v, 0, false) & 0xff);
}

// ---------------- CSR build: two-level counting sort ----------------
// p1 two-phase: count -> reserve -> re-read & scatter (dense bucket writes)

__global__ __launch_bounds__(256) void k_p1(const int* __restrict__ srcs,
                                            const int* __restrict__ dsts,
                                            int* __restrict__ bcount,
                                            int* __restrict__ bbuf) {
  __shared__ int lcnt[NBK];
  __shared__ int lbase[NBK];
  int tid = threadIdx.x;
  for (int i = tid; i < NBK; i += 256) lcnt[i] = 0;
  __syncthreads();
  int e0 = blockIdx.x * EPB;
  int e1 = (e0 + EPB < EE) ? (e0 + EPB) : EE;
  for (int e = e0 + tid; e < e1; e += 256)
    atomicAdd(&lcnt[dsts[e] >> 7], 1);
  __syncthreads();
  for (int i = tid; i < NBK; i += 256) {
    int c = lcnt[i];
    lbase[i] = c ? atomicAdd(&bcount[i], c) : 0;
  }
  __syncthreads();
  for (int i = tid; i < NBK; i += 256) lcnt[i] = 0;
  __syncthreads();
  for (int e = e0 + tid; e < e1; e += 256) {
    int d = dsts[e], s = srcs[e];
    int b = d >> 7;
    int r = atomicAdd(&lcnt[b], 1);
    bbuf[(size_t)b * BCAP + lbase[b] + r] = (s << 7) | (d & 127);
  }
}

__global__ void k_bscan(const int* __restrict__ bcount, int* __restrict__ bbase) {
  __shared__ int s[1024];
  int t = threadIdx.x;
  int v = 0;
  if (t < NBK) v = bcount[t] + min(BKW, NN - (t << 7));
  s[t] = v;
  __syncthreads();
  for (int off = 1; off < 1024; off <<= 1) {
    int u = (t >= off) ? s[t - off] : 0;
    __syncthreads();
    s[t] += u;
    __syncthreads();
  }
  if (t < NBK) bbase[t] = s[t] - v;
}

__global__ __launch_bounds__(256) void k_p2(const int* __restrict__ bcount,
                                            const int* __restrict__ bbase,
                                            const int* __restrict__ bbuf,
                                            int* __restrict__ offsets,
                                            int* __restrict__ edge_src) {
  __shared__ int cnt[BKW];
  __shared__ int s1[BKW];
  __shared__ int cur[BKW];
  int b = blockIdx.x, tid = threadIdx.x;
  int d0 = b << 7;
  int width = min(BKW, NN - d0);
  int n = bcount[b];
  int base = bbase[b];
  const int* buf = bbuf + (size_t)b * BCAP;
  if (tid < BKW) cnt[tid] = (tid < width) ? 1 : 0;
  __syncthreads();
  for (int i = tid; i < n; i += 256) atomicAdd(&cnt[buf[i] & 127], 1);
  __syncthreads();
  if (tid < BKW) s1[tid] = cnt[tid];
  __syncthreads();
  for (int off = 1; off < BKW; off <<= 1) {
    int u = (tid < BKW && tid >= off) ? s1[tid - off] : 0;
    __syncthreads();
    if (tid < BKW) s1[tid] += u;
    __syncthreads();
  }
  if (tid < width) {
    int excl = s1[tid] - cnt[tid];
    offsets[d0 + tid] = base + excl;
    edge_src[base + excl] = d0 + tid;   // self-loop first
    cur[tid] = excl + 1;
  }
  if (b == 0 && tid == 0) offsets[NN] = ET;
  __syncthreads();
  for (int i = tid; i < n; i += 256) {
    int p = buf[i];
    int pos = atomicAdd(&cur[p & 127], 1);
    edge_src[base + pos] = p >> 7;
  }
}

// ---------------- Layer 1: MFMA h1 = x @ W1 -> 64 B fp8 records (one line) ----------------
// D layout (16x16x32): row = (lane>>4)*4 + reg, col = lane&15.

__global__ __launch_bounds__(256) void k_gemm1(
    const float* __restrict__ x, const float* __restrict__ W1,
    const float* __restrict__ a1d,
    unsigned char* __restrict__ P1, float* __restrict__ ed1) {
  __shared__ _Float16 Wb[16 * 64 * 8];   // 16 KB, fragment-major
  int tid = threadIdx.x;
  for (int idx = tid; idx < 16 * 64; idx += 256) {
    int f = idx >> 6, l = idx & 63;
    int nt = f >> 2, kk = f & 3;
    int ql = l >> 4, cl = l & 15;
    int col = nt * 16 + cl;
    int k0 = kk * 32 + ql * 8;
    v8h tmp;
#pragma unroll
    for (int j = 0; j < 8; ++j) tmp[j] = (_Float16)W1[(k0 + j) * 64 + col];
    *reinterpret_cast<v8h*>(&Wb[idx * 8]) = tmp;
  }
  __syncthreads();
  int wv = tid >> 6, lane = tid & 63;
  int q = lane >> 4, c = lane & 15;
  v8h bf[16];
#pragma unroll
  for (int f = 0; f < 16; ++f)
    bf[f] = *reinterpret_cast<const v8h*>(&Wb[(f * 64 + lane) * 8]);
  float a1d_l[4];
#pragma unroll
  for (int nt = 0; nt < 4; ++nt) a1d_l[nt] = a1d[nt * 16 + c];
  for (int t = 0; t < 4; ++t) {
    int n0 = blockIdx.x * 256 + wv * 64 + t * 16;
    int row = n0 + c;
    row = (row < NN) ? row : (NN - 1);
    v4f acc[4] = {{0.f,0.f,0.f,0.f},{0.f,0.f,0.f,0.f},{0.f,0.f,0.f,0.f},{0.f,0.f,0.f,0.f}};
#pragma unroll
    for (int kk = 0; kk < 4; ++kk) {
      const float* xp = x + (size_t)row * 128 + kk * 32 + q * 8;
      float4 x0 = *reinterpret_cast<const float4*>(xp);
      float4 x1 = *reinterpret_cast<const float4*>(xp + 4);
      v8h af;
      af[0] = (_Float16)x0.x; af[1] = (_Float16)x0.y;
      af[2] = (_Float16)x0.z; af[3] = (_Float16)x0.w;
      af[4] = (_Float16)x1.x; af[5] = (_Float16)x1.y;
      af[6] = (_Float16)x1.z; af[7] = (_Float16)x1.w;
#pragma unroll
      for (int nt = 0; nt < 4; ++nt)
        acc[nt] = __builtin_amdgcn_mfma_f32_16x16x32_f16(af, bf[nt * 4 + kk], acc[nt], 0, 0, 0);
    }
#pragma unroll
    for (int nt = 0; nt < 4; ++nt) {
#pragma unroll
      for (int r = 0; r < 4; ++r) {
        float val = acc[nt][r];
        float vd = val * a1d_l[nt];
        vd += __shfl_xor(vd, 1); vd += __shfl_xor(vd, 2); vd += __shfl_xor(vd, 4);
        int node = n0 + q * 4 + r;
        if (node < NN) {
          P1[((size_t)node << 6) + nt * 16 + c] = to_fp8(val);
          if ((c & 7) == 0) ed1[node * 8 + 2 * nt + (c >> 3)] = vd;
        }
      }
    }
  }
}

// ---------------- Layer 1 aggregation: 8 dsts/wave, es recomputed, unroll 8 ----------------

__global__ __launch_bounds__(256) void k_agg1(
    const int* __restrict__ offsets, const int* __restrict__ edge_src,
    const unsigned char* __restrict__ P1, const float* __restrict__ a1s,
    const float* __restrict__ ed1, __half* __restrict__ x2) {
  int wv = threadIdx.x >> 6, lane = threadIdx.x & 63;
  int g = lane >> 3, p = lane & 7;        // group g: dst; lane p: head p, feats 8p..8p+7
  int dst = blockIdx.x * 32 + wv * 8 + g;
  float edv = ed1[dst * 8 + p];
  float4 as0 = *reinterpret_cast<const float4*>(a1s + p * 8);
  float4 as1 = *reinterpret_cast<const float4*>(a1s + p * 8 + 4);
  int beg = offsets[dst], end = offsets[dst + 1];
  int deg = end - beg;                    // >= 1 (self-loop)
  int md = deg;
#pragma unroll
  for (int o = 8; o < 64; o <<= 1) md = max(md, __shfl_xor(md, o, 64));
  float l = 0.f;
  float a[8] = {0.f, 0.f, 0.f, 0.f, 0.f, 0.f, 0.f, 0.f};
  for (int t = 0; t < md; t += 8) {
    int src[8]; uint2 raw[8];
#pragma unroll
    for (int i = 0; i < 8; ++i) {
      int idx = t + i;
      int ci = beg + ((idx < deg) ? idx : (deg - 1));
      src[i] = edge_src[ci];
    }
#pragma unroll
    for (int i = 0; i < 8; ++i)
      raw[i] = *reinterpret_cast<const uint2*>(P1 + ((size_t)src[i] << 6) + (p << 3));
#pragma unroll
    for (int i = 0; i < 8; ++i) {
      v2f f01 = __builtin_amdgcn_cvt_pk_f32_fp8(raw[i].x, false);
      v2f f23 = __builtin_amdgcn_cvt_pk_f32_fp8(raw[i].x, true);
      v2f f45 = __builtin_amdgcn_cvt_pk_f32_fp8(raw[i].y, false);
      v2f f67 = __builtin_amdgcn_cvt_pk_f32_fp8(raw[i].y, true);
      // recompute e_src for head p from the fp8 fragment
      float es = f01.x * as0.x + f01.y * as0.y + f23.x * as0.z + f23.y * as0.w
               + f45.x * as1.x + f45.y * as1.y + f67.x * as1.z + f67.y * as1.w;
      float e = lrelu(es + edv);
      float pr = (t + i < deg) ? __expf(e) : 0.f;   // |e|<3 provably: no max-shift
      l += pr;
      a[0] += pr * f01.x; a[1] += pr * f01.y;
      a[2] += pr * f23.x; a[3] += pr * f23.y;
      a[4] += pr * f45.x; a[5] += pr * f45.y;
      a[6] += pr * f67.x; a[7] += pr * f67.y;
    }
  }
  float rl = 1.f / l;
  union { __half h[8]; uint4 u; } pk;
#pragma unroll
  for (int i = 0; i < 8; ++i) {
    float v = a[i] * rl;
    v = (v > 0.f) ? v : (__expf(v) - 1.f);   // ELU fused
    pk.h[i] = __float2half(v);
  }
  *reinterpret_cast<uint4*>(x2 + ((size_t)dst << 6) + (p << 3)) = pk.u;
}

// ---------------- Layer 2: MFMA h2 = x2 @ W2 -> 64 B records (h fp8 @0..39, es fp16 @40) ----------------

__global__ __launch_bounds__(256) void k_gemm2(
    const __half* __restrict__ x2, const float* __restrict__ W2,
    const float* __restrict__ a2s, const float* __restrict__ a2d,
    unsigned char* __restrict__ P2, float* __restrict__ ed2) {
  __shared__ _Float16 Wb[6 * 64 * 8];   // 6 KB
  int tid = threadIdx.x;
  for (int idx = tid; idx < 6 * 64; idx += 256) {
    int f = idx >> 6, l = idx & 63;
    int nt = f >> 1, kk = f & 1;
    int ql = l >> 4, cl = l & 15;
    int col = nt * 16 + cl;
    int k0 = kk * 32 + ql * 8;
    v8h tmp;
#pragma unroll
    for (int j = 0; j < 8; ++j)
      tmp[j] = (col < 40) ? (_Float16)W2[(k0 + j) * 40 + col] : (_Float16)0.f;
    *reinterpret_cast<v8h*>(&Wb[idx * 8]) = tmp;
  }
  __syncthreads();
  int wv = tid >> 6, lane = tid & 63;
  int q = lane >> 4, c = lane & 15;
  v8h bf[6];
#pragma unroll
  for (int f = 0; f < 6; ++f)
    bf[f] = *reinterpret_cast<const v8h*>(&Wb[(f * 64 + lane) * 8]);
  float a2s_l[3], a2d_l[3];
#pragma unroll
  for (int nt = 0; nt < 3; ++nt) {
    int n = nt * 16 + c;
    a2s_l[nt] = (n < 40) ? a2s[n] : 0.f;
    a2d_l[nt] = (n < 40) ? a2d[n] : 0.f;
  }
  for (int t = 0; t < 4; ++t) {
    int n0 = blockIdx.x * 256 + wv * 64 + t * 16;
    int row = n0 + c;
    row = (row < NN) ? row : (NN - 1);
    v4f acc[3] = {{0.f,0.f,0.f,0.f},{0.f,0.f,0.f,0.f},{0.f,0.f,0.f,0.f}};
#pragma unroll
    for (int kk = 0; kk < 2; ++kk) {
      v8h af = *reinterpret_cast<const v8h*>(x2 + (size_t)row * 64 + kk * 32 + q * 8);
#pragma unroll
      for (int nt = 0; nt < 3; ++nt)
        acc[nt] = __builtin_amdgcn_mfma_f32_16x16x32_f16(af, bf[nt * 2 + kk], acc[nt], 0, 0, 0);
    }
#pragma unroll
    for (int r = 0; r < 4; ++r) {
      float v0 = acc[0][r], v1 = acc[1][r], v2 = acc[2][r];
      float s = v0 * a2s_l[0] + v1 * a2s_l[1] + v2 * a2s_l[2];
      float d = v0 * a2d_l[0] + v1 * a2d_l[1] + v2 * a2d_l[2];
      s += __shfl_xor(s, 1); s += __shfl_xor(s, 2); s += __shfl_xor(s, 4); s += __shfl_xor(s, 8);
      d += __shfl_xor(d, 1); d += __shfl_xor(d, 2); d += __shfl_xor(d, 4); d += __shfl_xor(d, 8);
      int node = n0 + q * 4 + r;
      if (node < NN) {
        unsigned char* rec = P2 + ((size_t)node << 6);
        if (c < 8) rec[32 + c] = to_fp8(v2);          // nt=2: classes 32..39
        rec[c]      = to_fp8(v0);                     // nt=0: classes 0..15
        rec[16 + c] = to_fp8(v1);                     // nt=1: classes 16..31
        if (c == 0) {
          *reinterpret_cast<__half*>(rec + 40) = __float2half(s);
          ed2[node] = d;
        }
      }
    }
  }
}

// ---------------- Layer 2 aggregation + log_softmax: 4 dsts/wave x 16 lanes ----------------
// exp-dedup: lane p&7 computes pr for edge p&7, broadcast via shuffle.

__global__ __launch_bounds__(256) void k_agg2(
    const int* __restrict__ offsets, const int* __restrict__ edge_src,
    const unsigned char* __restrict__ P2, const float* __restrict__ ed2,
    float* __restrict__ out) {
  int wv = threadIdx.x >> 6, lane = threadIdx.x & 63;
  int g = lane >> 4, p = lane & 15;   // lane p: classes 4p..4p+3; active p<10
  bool act = p < 10;
  int cp = act ? p : 0;
  int dst = blockIdx.x * 16 + wv * 4 + g;
  float edv = ed2[dst];
  int beg = offsets[dst], end = offsets[dst + 1];
  int deg = end - beg;
  int md = deg;
#pragma unroll
  for (int o = 16; o < 64; o <<= 1) md = max(md, __shfl_xor(md, o, 64));
  int gbase = lane & 48;              // first lane of this group
  int me = p & 7;                     // the edge this lane computes exp for
  float l = 0.f;
  float a[4] = {0.f, 0.f, 0.f, 0.f};
  for (int t = 0; t < md; t += 8) {
    int src[8]; unsigned raw[8];
#pragma unroll
    for (int i = 0; i < 8; ++i) {
      int ix = t + i;
      int ci = beg + ((ix < deg) ? ix : (deg - 1));
      src[i] = edge_src[ci];
    }
    // one es-load + one exp chain per lane, covering edge (p&7) of this group
    float myes = __half2float(*reinterpret_cast<const __half*>(
        P2 + ((size_t)src[me] << 6) + 40));
    float mye = lrelu(myes + edv);
    float mypr = (t + me < deg) ? __expf(mye) : 0.f;
#pragma unroll
    for (int i = 0; i < 8; ++i)
      raw[i] = *reinterpret_cast<const unsigned*>(P2 + ((size_t)src[i] << 6) + (cp << 2));
#pragma unroll
    for (int i = 0; i < 8; ++i) {
      float pr = __shfl(mypr, gbase | i, 64);
      v2f f01 = __builtin_amdgcn_cvt_pk_f32_fp8(raw[i], false);
      v2f f23 = __builtin_amdgcn_cvt_pk_f32_fp8(raw[i], true);
      l += pr;
      a[0] += pr * f01.x; a[1] += pr * f01.y;
      a[2] += pr * f23.x; a[3] += pr * f23.y;
    }
  }
  float rl = 1.f / l;
  float v0 = a[0] * rl, v1 = a[1] * rl, v2 = a[2] * rl, v3 = a[3] * rl;
  float red = act ? fmaxf(fmaxf(v0, v1), fmaxf(v2, v3)) : -INFINITY;
#pragma unroll
  for (int o = 1; o < 16; o <<= 1) red = fmaxf(red, __shfl_xor(red, o, 64));
  float se = act ? (__expf(v0 - red) + __expf(v1 - red) + __expf(v2 - red) + __expf(v3 - red)) : 0.f;
#pragma unroll
  for (int o = 1; o < 16; o <<= 1) se += __shfl_xor(se, o, 64);
  float ls = red + __logf(se);
  if (act) {
    float4 o4 = make_float4(v0 - ls, v1 - ls, v2 - ls, v3 - ls);
    *reinterpret_cast<float4*>(out + (size_t)dst * 40 + (p << 2)) = o4;
  }
}

// ---------------- launch ----------------

extern "C" void kernel_launch(void* const* d_in, const int* in_sizes, int n_in,
                              void* d_out, int out_size, void* d_ws, size_t ws_size,
                              hipStream_t stream) {
  const float* x   = (const float*)d_in[0];
  const int*   adj = (const int*)d_in[1];     // [2, EE]
  const float* W1  = (const float*)d_in[2];
  const float* a1s = (const float*)d_in[3];
  const float* a1d = (const float*)d_in[4];
  const float* W2  = (const float*)d_in[5];
  const float* a2s = (const float*)d_in[6];
  const float* a2d = (const float*)d_in[7];
  float* out = (float*)d_out;

  const int* srcs = adj;
  const int* dsts = adj + EE;

  char* w = (char*)d_ws;
  size_t off = 0;
  auto alloc = [&](size_t bytes) -> void* {
    void* p = w + off;
    off = (off + bytes + 255) & ~(size_t)255;
    return p;
  };
  int* offsets      = (int*)alloc((size_t)(NN + 1) * 4);
  int* edge_src     = (int*)alloc((size_t)ET * 4);
  int* bcount       = (int*)alloc((size_t)NBK * 4);
  int* bbase        = (int*)alloc((size_t)NBK * 4);
  unsigned char* P1 = (unsigned char*)alloc((size_t)NN * 64);  // 6.4 MB fp8 h, 64 B/line recs
  float* ed1        = (float*)alloc((size_t)NN * 8 * 4);       // 3.2 MB
  __half* x2        = (__half*)alloc((size_t)NN * 64 * 2);     // 12.8 MB
  int* bbuf         = (int*)alloc((size_t)NBK * BCAP * 4);     // 16 MB
  // layer-2 buffers alias layer-1 (P1/ed1 dead after k_agg1):
  unsigned char* P2 = P1;     // 6.4 MB == 6.4 MB
  float* ed2 = ed1;

  hipMemsetAsync(bcount, 0, (size_t)NBK * 4, stream);
  k_p1<<<NB_P1, 256, 0, stream>>>(srcs, dsts, bcount, bbuf);
  k_bscan<<<1, 1024, 0, stream>>>(bcount, bbase);
  k_p2<<<NBK, 256, 0, stream>>>(bcount, bbase, bbuf, offsets, edge_src);

  k_gemm1<<<NB_G, 256, 0, stream>>>(x, W1, a1d, P1, ed1);
  k_agg1<<<NN / 32, 256, 0, stream>>>(offsets, edge_src, P1, a1s, ed1, x2);
  k_gemm2<<<NB_G, 256, 0, stream>>>(x2, W2, a2s, a2d, P2, ed2);
  k_agg2<<<NN / 16, 256, 0, stream>>>(offsets, edge_src, P2, ed2, out);
}

// Round 16
// 307.312 us; speedup vs baseline: 1.0823x; 1.0823x over previous
//
#include <hip/hip_runtime.h>
#include <hip/hip_fp16.h>
#include <math.h>

#define NN 100000
#define EE 3200000
#define ET (EE + NN)
#define BKW 128                       // dsts per bucket
#define NBK ((NN + BKW - 1) / BKW)    // 782 buckets
#define BCAP 5120                     // per-bucket capacity
#define EPB 4096                      // edges per p1 block (one-phase, 782 blocks)
#define NB_P1 ((EE + EPB - 1) / EPB)  // 782
#define NB_G 391                      // gemm blocks: 391*256 = 100096 >= NN

typedef float v2f __attribute__((ext_vector_type(2)));
typedef float v4f __attribute__((ext_vector_type(4)));
typedef _Float16 v8h __attribute__((ext_vector_type(8)));

__device__ __forceinline__ float lrelu(float v) { return fmaxf(v, 0.2f * v); }

__device__ __forceinline__ unsigned char to_fp8(float v) {
  return (unsigned char)(__builtin_amdgcn_cvt_pk_fp8_f32(v, v, 0, false) & 0xff);
}

// ---------------- CSR build: two-level counting sort ----------------

__global__ __launch_bounds__(256) void k_p1(const int* __restrict__ srcs,
                                            const int* __restrict__ dsts,
                                            int* __restrict__ bcount,
                                            int* __restrict__ bbuf) {
  __shared__ int lcnt[NBK];
  __shared__ int lbase[NBK];
  int tid = threadIdx.x;
  for (int i = tid; i < NBK; i += 256) lcnt[i] = 0;
  __syncthreads();
  int e0 = blockIdx.x * EPB;
  int rank[16], bkt[16], pk[16];
#pragma unroll
  for (int i = 0; i < 16; ++i) {
    int e = e0 + tid + i * 256;
    bkt[i] = -1;
    if (e < EE) {
      int d = dsts[e];
      int s = srcs[e];
      int b = d >> 7;
      rank[i] = atomicAdd(&lcnt[b], 1);
      bkt[i] = b;
      pk[i] = (s << 7) | (d & 127);
    }
  }
  __syncthreads();
  for (int i = tid; i < NBK; i += 256) {
    int c = lcnt[i];
    lbase[i] = c ? atomicAdd(&bcount[i], c) : 0;
  }
  __syncthreads();
#pragma unroll
  for (int i = 0; i < 16; ++i) {
    if (bkt[i] >= 0) {
      bbuf[(size_t)bkt[i] * BCAP + lbase[bkt[i]] + rank[i]] = pk[i];
    }
  }
}

__global__ void k_bscan(const int* __restrict__ bcount, int* __restrict__ bbase) {
  __shared__ int s[1024];
  int t = threadIdx.x;
  int v = 0;
  if (t < NBK) v = bcount[t] + min(BKW, NN - (t << 7));
  s[t] = v;
  __syncthreads();
  for (int off = 1; off < 1024; off <<= 1) {
    int u = (t >= off) ? s[t - off] : 0;
    __syncthreads();
    s[t] += u;
    __syncthreads();
  }
  if (t < NBK) bbase[t] = s[t] - v;
}

__global__ __launch_bounds__(256) void k_p2(const int* __restrict__ bcount,
                                            const int* __restrict__ bbase,
                                            const int* __restrict__ bbuf,
                                            int* __restrict__ offsets,
                                            int* __restrict__ edge_src) {
  __shared__ int cnt[BKW];
  __shared__ int s1[BKW];
  __shared__ int cur[BKW];
  int b = blockIdx.x, tid = threadIdx.x;
  int d0 = b << 7;
  int width = min(BKW, NN - d0);
  int n = bcount[b];
  int base = bbase[b];
  const int* buf = bbuf + (size_t)b * BCAP;
  if (tid < BKW) cnt[tid] = (tid < width) ? 1 : 0;
  __syncthreads();
  for (int i = tid; i < n; i += 256) atomicAdd(&cnt[buf[i] & 127], 1);
  __syncthreads();
  if (tid < BKW) s1[tid] = cnt[tid];
  __syncthreads();
  for (int off = 1; off < BKW; off <<= 1) {
    int u = (tid < BKW && tid >= off) ? s1[tid - off] : 0;
    __syncthreads();
    if (tid < BKW) s1[tid] += u;
    __syncthreads();
  }
  if (tid < width) {
    int excl = s1[tid] - cnt[tid];
    offsets[d0 + tid] = base + excl;
    edge_src[base + excl] = d0 + tid;   // self-loop first
    cur[tid] = excl + 1;
  }
  if (b == 0 && tid == 0) offsets[NN] = ET;
  __syncthreads();
  for (int i = tid; i < n; i += 256) {
    int p = buf[i];
    int pos = atomicAdd(&cur[p & 127], 1);
    edge_src[base + pos] = p >> 7;
  }
}

// ---------------- Layer 1: MFMA h1 = x @ W1 -> 64 B fp8 records (one line) ----------------
// D layout (16x16x32): row = (lane>>4)*4 + reg, col = lane&15.

__global__ __launch_bounds__(256) void k_gemm1(
    const float* __restrict__ x, const float* __restrict__ W1,
    const float* __restrict__ a1d,
    unsigned char* __restrict__ P1, float* __restrict__ ed1) {
  __shared__ _Float16 Wb[16 * 64 * 8];   // 16 KB, fragment-major
  int tid = threadIdx.x;
  for (int idx = tid; idx < 16 * 64; idx += 256) {
    int f = idx >> 6, l = idx & 63;
    int nt = f >> 2, kk = f & 3;
    int ql = l >> 4, cl = l & 15;
    int col = nt * 16 + cl;
    int k0 = kk * 32 + ql * 8;
    v8h tmp;
#pragma unroll
    for (int j = 0; j < 8; ++j) tmp[j] = (_Float16)W1[(k0 + j) * 64 + col];
    *reinterpret_cast<v8h*>(&Wb[idx * 8]) = tmp;
  }
  __syncthreads();
  int wv = tid >> 6, lane = tid & 63;
  int q = lane >> 4, c = lane & 15;
  v8h bf[16];
#pragma unroll
  for (int f = 0; f < 16; ++f)
    bf[f] = *reinterpret_cast<const v8h*>(&Wb[(f * 64 + lane) * 8]);
  float a1d_l[4];
#pragma unroll
  for (int nt = 0; nt < 4; ++nt) a1d_l[nt] = a1d[nt * 16 + c];
  for (int t = 0; t < 4; ++t) {
    int n0 = blockIdx.x * 256 + wv * 64 + t * 16;
    int row = n0 + c;
    row = (row < NN) ? row : (NN - 1);
    v4f acc[4] = {{0.f,0.f,0.f,0.f},{0.f,0.f,0.f,0.f},{0.f,0.f,0.f,0.f},{0.f,0.f,0.f,0.f}};
#pragma unroll
    for (int kk = 0; kk < 4; ++kk) {
      const float* xp = x + (size_t)row * 128 + kk * 32 + q * 8;
      float4 x0 = *reinterpret_cast<const float4*>(xp);
      float4 x1 = *reinterpret_cast<const float4*>(xp + 4);
      v8h af;
      af[0] = (_Float16)x0.x; af[1] = (_Float16)x0.y;
      af[2] = (_Float16)x0.z; af[3] = (_Float16)x0.w;
      af[4] = (_Float16)x1.x; af[5] = (_Float16)x1.y;
      af[6] = (_Float16)x1.z; af[7] = (_Float16)x1.w;
#pragma unroll
      for (int nt = 0; nt < 4; ++nt)
        acc[nt] = __builtin_amdgcn_mfma_f32_16x16x32_f16(af, bf[nt * 4 + kk], acc[nt], 0, 0, 0);
    }
#pragma unroll
    for (int nt = 0; nt < 4; ++nt) {
#pragma unroll
      for (int r = 0; r < 4; ++r) {
        float val = acc[nt][r];
        float vd = val * a1d_l[nt];
        vd += __shfl_xor(vd, 1); vd += __shfl_xor(vd, 2); vd += __shfl_xor(vd, 4);
        int node = n0 + q * 4 + r;
        if (node < NN) {
          P1[((size_t)node << 6) + nt * 16 + c] = to_fp8(val);
          if ((c & 7) == 0) ed1[node * 8 + 2 * nt + (c >> 3)] = vd;
        }
      }
    }
  }
}

// ---------------- Layer 1 aggregation: 8 dsts/wave, es recomputed, unroll 8 ----------------

__global__ __launch_bounds__(256) void k_agg1(
    const int* __restrict__ offsets, const int* __restrict__ edge_src,
    const unsigned char* __restrict__ P1, const float* __restrict__ a1s,
    const float* __restrict__ ed1, __half* __restrict__ x2) {
  int wv = threadIdx.x >> 6, lane = threadIdx.x & 63;
  int g = lane >> 3, p = lane & 7;        // group g: dst; lane p: head p, feats 8p..8p+7
  int dst = blockIdx.x * 32 + wv * 8 + g;
  float edv = ed1[dst * 8 + p];
  float4 as0 = *reinterpret_cast<const float4*>(a1s + p * 8);
  float4 as1 = *reinterpret_cast<const float4*>(a1s + p * 8 + 4);
  int beg = offsets[dst], end = offsets[dst + 1];
  int deg = end - beg;                    // >= 1 (self-loop)
  int md = deg;
#pragma unroll
  for (int o = 8; o < 64; o <<= 1) md = max(md, __shfl_xor(md, o, 64));
  float l = 0.f;
  float a[8] = {0.f, 0.f, 0.f, 0.f, 0.f, 0.f, 0.f, 0.f};
  for (int t = 0; t < md; t += 8) {
    int src[8]; uint2 raw[8];
#pragma unroll
    for (int i = 0; i < 8; ++i) {
      int idx = t + i;
      int ci = beg + ((idx < deg) ? idx : (deg - 1));
      src[i] = edge_src[ci];
    }
#pragma unroll
    for (int i = 0; i < 8; ++i)
      raw[i] = *reinterpret_cast<const uint2*>(P1 + ((size_t)src[i] << 6) + (p << 3));
#pragma unroll
    for (int i = 0; i < 8; ++i) {
      v2f f01 = __builtin_amdgcn_cvt_pk_f32_fp8(raw[i].x, false);
      v2f f23 = __builtin_amdgcn_cvt_pk_f32_fp8(raw[i].x, true);
      v2f f45 = __builtin_amdgcn_cvt_pk_f32_fp8(raw[i].y, false);
      v2f f67 = __builtin_amdgcn_cvt_pk_f32_fp8(raw[i].y, true);
      // recompute e_src for head p from the fp8 fragment
      float es = f01.x * as0.x + f01.y * as0.y + f23.x * as0.z + f23.y * as0.w
               + f45.x * as1.x + f45.y * as1.y + f67.x * as1.z + f67.y * as1.w;
      float e = lrelu(es + edv);
      float pr = (t + i < deg) ? __expf(e) : 0.f;   // |e|<3 provably: no max-shift
      l += pr;
      a[0] += pr * f01.x; a[1] += pr * f01.y;
      a[2] += pr * f23.x; a[3] += pr * f23.y;
      a[4] += pr * f45.x; a[5] += pr * f45.y;
      a[6] += pr * f67.x; a[7] += pr * f67.y;
    }
  }
  float rl = 1.f / l;
  union { __half h[8]; uint4 u; } pk;
#pragma unroll
  for (int i = 0; i < 8; ++i) {
    float v = a[i] * rl;
    v = (v > 0.f) ? v : (__expf(v) - 1.f);   // ELU fused
    pk.h[i] = __float2half(v);
  }
  *reinterpret_cast<uint4*>(x2 + ((size_t)dst << 6) + (p << 3)) = pk.u;
}

// ---------------- Layer 2: MFMA h2 = x2 @ W2 -> 64 B records (h fp8 @0..39, es fp16 @40) ----------------

__global__ __launch_bounds__(256) void k_gemm2(
    const __half* __restrict__ x2, const float* __restrict__ W2,
    const float* __restrict__ a2s, const float* __restrict__ a2d,
    unsigned char* __restrict__ P2, float* __restrict__ ed2) {
  __shared__ _Float16 Wb[6 * 64 * 8];   // 6 KB
  int tid = threadIdx.x;
  for (int idx = tid; idx < 6 * 64; idx += 256) {
    int f = idx >> 6, l = idx & 63;
    int nt = f >> 1, kk = f & 1;
    int ql = l >> 4, cl = l & 15;
    int col = nt * 16 + cl;
    int k0 = kk * 32 + ql * 8;
    v8h tmp;
#pragma unroll
    for (int j = 0; j < 8; ++j)
      tmp[j] = (col < 40) ? (_Float16)W2[(k0 + j) * 40 + col] : (_Float16)0.f;
    *reinterpret_cast<v8h*>(&Wb[idx * 8]) = tmp;
  }
  __syncthreads();
  int wv = tid >> 6, lane = tid & 63;
  int q = lane >> 4, c = lane & 15;
  v8h bf[6];
#pragma unroll
  for (int f = 0; f < 6; ++f)
    bf[f] = *reinterpret_cast<const v8h*>(&Wb[(f * 64 + lane) * 8]);
  float a2s_l[3], a2d_l[3];
#pragma unroll
  for (int nt = 0; nt < 3; ++nt) {
    int n = nt * 16 + c;
    a2s_l[nt] = (n < 40) ? a2s[n] : 0.f;
    a2d_l[nt] = (n < 40) ? a2d[n] : 0.f;
  }
  for (int t = 0; t < 4; ++t) {
    int n0 = blockIdx.x * 256 + wv * 64 + t * 16;
    int row = n0 + c;
    row = (row < NN) ? row : (NN - 1);
    v4f acc[3] = {{0.f,0.f,0.f,0.f},{0.f,0.f,0.f,0.f},{0.f,0.f,0.f,0.f}};
#pragma unroll
    for (int kk = 0; kk < 2; ++kk) {
      v8h af = *reinterpret_cast<const v8h*>(x2 + (size_t)row * 64 + kk * 32 + q * 8);
#pragma unroll
      for (int nt = 0; nt < 3; ++nt)
        acc[nt] = __builtin_amdgcn_mfma_f32_16x16x32_f16(af, bf[nt * 2 + kk], acc[nt], 0, 0, 0);
    }
#pragma unroll
    for (int r = 0; r < 4; ++r) {
      float v0 = acc[0][r], v1 = acc[1][r], v2 = acc[2][r];
      float s = v0 * a2s_l[0] + v1 * a2s_l[1] + v2 * a2s_l[2];
      float d = v0 * a2d_l[0] + v1 * a2d_l[1] + v2 * a2d_l[2];
      s += __shfl_xor(s, 1); s += __shfl_xor(s, 2); s += __shfl_xor(s, 4); s += __shfl_xor(s, 8);
      d += __shfl_xor(d, 1); d += __shfl_xor(d, 2); d += __shfl_xor(d, 4); d += __shfl_xor(d, 8);
      int node = n0 + q * 4 + r;
      if (node < NN) {
        unsigned char* rec = P2 + ((size_t)node << 6);
        if (c < 8) rec[32 + c] = to_fp8(v2);          // nt=2: classes 32..39
        rec[c]      = to_fp8(v0);                     // nt=0: classes 0..15
        rec[16 + c] = to_fp8(v1);                     // nt=1: classes 16..31
        if (c == 0) {
          *reinterpret_cast<__half*>(rec + 40) = __float2half(s);
          ed2[node] = d;
        }
      }
    }
  }
}

// ---------------- Layer 2 aggregation + log_softmax: 4 dsts/wave x 16 lanes ----------------
// exp-dedup: lane p&7 computes pr for edge p&7, broadcast via shuffle.

__global__ __launch_bounds__(256) void k_agg2(
    const int* __restrict__ offsets, const int* __restrict__ edge_src,
    const unsigned char* __restrict__ P2, const float* __restrict__ ed2,
    float* __restrict__ out) {
  int wv = threadIdx.x >> 6, lane = threadIdx.x & 63;
  int g = lane >> 4, p = lane & 15;   // lane p: classes 4p..4p+3; active p<10
  bool act = p < 10;
  int cp = act ? p : 0;
  int dst = blockIdx.x * 16 + wv * 4 + g;
  float edv = ed2[dst];
  int beg = offsets[dst], end = offsets[dst + 1];
  int deg = end - beg;
  int md = deg;
#pragma unroll
  for (int o = 16; o < 64; o <<= 1) md = max(md, __shfl_xor(md, o, 64));
  int gbase = lane & 48;              // first lane of this group
  int me = p & 7;                     // the edge this lane computes exp for
  float l = 0.f;
  float a[4] = {0.f, 0.f, 0.f, 0.f};
  for (int t = 0; t < md; t += 8) {
    int src[8]; unsigned raw[8];
#pragma unroll
    for (int i = 0; i < 8; ++i) {
      int ix = t + i;
      int ci = beg + ((ix < deg) ? ix : (deg - 1));
      src[i] = edge_src[ci];
    }
    // one es-load + one exp chain per lane, covering edge (p&7) of this group
    float myes = __half2float(*reinterpret_cast<const __half*>(
        P2 + ((size_t)src[me] << 6) + 40));
    float mye = lrelu(myes + edv);
    float mypr = (t + me < deg) ? __expf(mye) : 0.f;
#pragma unroll
    for (int i = 0; i < 8; ++i)
      raw[i] = *reinterpret_cast<const unsigned*>(P2 + ((size_t)src[i] << 6) + (cp << 2));
#pragma unroll
    for (int i = 0; i < 8; ++i) {
      float pr = __shfl(mypr, gbase | i, 64);
      v2f f01 = __builtin_amdgcn_cvt_pk_f32_fp8(raw[i], false);
      v2f f23 = __builtin_amdgcn_cvt_pk_f32_fp8(raw[i], true);
      l += pr;
      a[0] += pr * f01.x; a[1] += pr * f01.y;
      a[2] += pr * f23.x; a[3] += pr * f23.y;
    }
  }
  float rl = 1.f / l;
  float v0 = a[0] * rl, v1 = a[1] * rl, v2 = a[2] * rl, v3 = a[3] * rl;
  float red = act ? fmaxf(fmaxf(v0, v1), fmaxf(v2, v3)) : -INFINITY;
#pragma unroll
  for (int o = 1; o < 16; o <<= 1) red = fmaxf(red, __shfl_xor(red, o, 64));
  float se = act ? (__expf(v0 - red) + __expf(v1 - red) + __expf(v2 - red) + __expf(v3 - red)) : 0.f;
#pragma unroll
  for (int o = 1; o < 16; o <<= 1) se += __shfl_xor(se, o, 64);
  float ls = red + __logf(se);
  if (act) {
    float4 o4 = make_float4(v0 - ls, v1 - ls, v2 - ls, v3 - ls);
    *reinterpret_cast<float4*>(out + (size_t)dst * 40 + (p << 2)) = o4;
  }
}

// ---------------- launch ----------------

extern "C" void kernel_launch(void* const* d_in, const int* in_sizes, int n_in,
                              void* d_out, int out_size, void* d_ws, size_t ws_size,
                              hipStream_t stream) {
  const float* x   = (const float*)d_in[0];
  const int*   adj = (const int*)d_in[1];     // [2, EE]
  const float* W1  = (const float*)d_in[2];
  const float* a1s = (const float*)d_in[3];
  const float* a1d = (const float*)d_in[4];
  const float* W2  = (const float*)d_in[5];
  const float* a2s = (const float*)d_in[6];
  const float* a2d = (const float*)d_in[7];
  float* out = (float*)d_out;

  const int* srcs = adj;
  const int* dsts = adj + EE;

  char* w = (char*)d_ws;
  size_t off = 0;
  auto alloc = [&](size_t bytes) -> void* {
    void* p = w + off;
    off = (off + bytes + 255) & ~(size_t)255;
    return p;
  };
  int* offsets      = (int*)alloc((size_t)(NN + 1) * 4);
  int* edge_src     = (int*)alloc((size_t)ET * 4);
  int* bcount       = (int*)alloc((size_t)NBK * 4);
  int* bbase        = (int*)alloc((size_t)NBK * 4);
  unsigned char* P1 = (unsigned char*)alloc((size_t)NN * 64);  // 6.4 MB fp8 h, 64 B/line recs
  float* ed1        = (float*)alloc((size_t)NN * 8 * 4);       // 3.2 MB
  __half* x2        = (__half*)alloc((size_t)NN * 64 * 2);     // 12.8 MB
  int* bbuf         = (int*)alloc((size_t)NBK * BCAP * 4);     // 16 MB
  // layer-2 buffers alias layer-1 (P1/ed1 dead after k_agg1):
  unsigned char* P2 = P1;     // 6.4 MB == 6.4 MB
  float* ed2 = ed1;

  hipMemsetAsync(bcount, 0, (size_t)NBK * 4, stream);
  k_p1<<<NB_P1, 256, 0, stream>>>(srcs, dsts, bcount, bbuf);
  k_bscan<<<1, 1024, 0, stream>>>(bcount, bbase);
  k_p2<<<NBK, 256, 0, stream>>>(bcount, bbase, bbuf, offsets, edge_src);

  k_gemm1<<<NB_G, 256, 0, stream>>>(x, W1, a1d, P1, ed1);
  k_agg1<<<NN / 32, 256, 0, stream>>>(offsets, edge_src, P1, a1s, ed1, x2);
  k_gemm2<<<NB_G, 256, 0, stream>>>(x2, W2, a2s, a2d, P2, ed2);
  k_agg2<<<NN / 16, 256, 0, stream>>>(offsets, edge_src, P2, ed2, out);
}

// Round 17
// 299.622 us; speedup vs baseline: 1.1100x; 1.0257x over previous
//
#include <hip/hip_runtime.h>
#include <hip/hip_fp16.h>
#include <math.h>

#define NN 100000
#define EE 3200000
#define ET (EE + NN)
#define BKW 128                       // dsts per bucket
#define NBK ((NN + BKW - 1) / BKW)    // 782 buckets
#define BCAP 5120                     // per-bucket capacity
#define EPB 4096                      // edges per p1 block (one-phase, 782 blocks)
#define NB_P1 ((EE + EPB - 1) / EPB)  // 782
#define NB_G 391                      // gemm blocks: 391*256 = 100096 >= NN

typedef float v2f __attribute__((ext_vector_type(2)));
typedef float v4f __attribute__((ext_vector_type(4)));
typedef _Float16 v8h __attribute__((ext_vector_type(8)));

__device__ __forceinline__ float lrelu(float v) { return fmaxf(v, 0.2f * v); }

__device__ __forceinline__ unsigned char to_fp8(float v) {
  return (unsigned char)(__builtin_amdgcn_cvt_pk_fp8_f32(v, v, 0, false) & 0xff);
}

// ---------------- Fused: CSR phase-1 bucket sort (blocks 0..NB_P1-1)
//                  + Layer-1 MFMA GEMM (blocks NB_P1..NB_P1+NB_G-1) ----------------
// Independent work: p1 reads adj, writes bcount/bbuf; gemm1 reads x/W1, writes P1/ed1.
// gemm1 D layout (16x16x32): row = (lane>>4)*4 + reg, col = lane&15.

__global__ __launch_bounds__(256) void k_p1g1(
    const int* __restrict__ srcs, const int* __restrict__ dsts,
    int* __restrict__ bcount, int* __restrict__ bbuf,
    const float* __restrict__ x, const float* __restrict__ W1,
    const float* __restrict__ a1d,
    unsigned char* __restrict__ P1, float* __restrict__ ed1) {
  __shared__ char smem[16 * 64 * 8 * 2];   // 16 KB union
  int tid = threadIdx.x;
  if (blockIdx.x < NB_P1) {
    // ---- p1: block-local bucket sort ----
    int* lcnt  = (int*)smem;
    int* lbase = lcnt + NBK;
    for (int i = tid; i < NBK; i += 256) lcnt[i] = 0;
    __syncthreads();
    int e0 = blockIdx.x * EPB;
    int rank[16], bkt[16], pk[16];
#pragma unroll
    for (int i = 0; i < 16; ++i) {
      int e = e0 + tid + i * 256;
      bkt[i] = -1;
      if (e < EE) {
        int d = dsts[e];
        int s = srcs[e];
        int b = d >> 7;
        rank[i] = atomicAdd(&lcnt[b], 1);
        bkt[i] = b;
        pk[i] = (s << 7) | (d & 127);
      }
    }
    __syncthreads();
    for (int i = tid; i < NBK; i += 256) {
      int c = lcnt[i];
      lbase[i] = c ? atomicAdd(&bcount[i], c) : 0;
    }
    __syncthreads();
#pragma unroll
    for (int i = 0; i < 16; ++i) {
      if (bkt[i] >= 0) {
        bbuf[(size_t)bkt[i] * BCAP + lbase[bkt[i]] + rank[i]] = pk[i];
      }
    }
    return;
  }
  // ---- gemm1 ----
  _Float16* Wb = (_Float16*)smem;   // 16 KB fragment-major
  int gbid = blockIdx.x - NB_P1;
  for (int idx = tid; idx < 16 * 64; idx += 256) {
    int f = idx >> 6, l = idx & 63;
    int nt = f >> 2, kk = f & 3;
    int ql = l >> 4, cl = l & 15;
    int col = nt * 16 + cl;
    int k0 = kk * 32 + ql * 8;
    v8h tmp;
#pragma unroll
    for (int j = 0; j < 8; ++j) tmp[j] = (_Float16)W1[(k0 + j) * 64 + col];
    *reinterpret_cast<v8h*>(&Wb[idx * 8]) = tmp;
  }
  __syncthreads();
  int wv = tid >> 6, lane = tid & 63;
  int q = lane >> 4, c = lane & 15;
  v8h bf[16];
#pragma unroll
  for (int f = 0; f < 16; ++f)
    bf[f] = *reinterpret_cast<const v8h*>(&Wb[(f * 64 + lane) * 8]);
  float a1d_l[4];
#pragma unroll
  for (int nt = 0; nt < 4; ++nt) a1d_l[nt] = a1d[nt * 16 + c];
  for (int t = 0; t < 4; ++t) {
    int n0 = gbid * 256 + wv * 64 + t * 16;
    int row = n0 + c;
    row = (row < NN) ? row : (NN - 1);
    v4f acc[4] = {{0.f,0.f,0.f,0.f},{0.f,0.f,0.f,0.f},{0.f,0.f,0.f,0.f},{0.f,0.f,0.f,0.f}};
#pragma unroll
    for (int kk = 0; kk < 4; ++kk) {
      const float* xp = x + (size_t)row * 128 + kk * 32 + q * 8;
      float4 x0 = *reinterpret_cast<const float4*>(xp);
      float4 x1 = *reinterpret_cast<const float4*>(xp + 4);
      v8h af;
      af[0] = (_Float16)x0.x; af[1] = (_Float16)x0.y;
      af[2] = (_Float16)x0.z; af[3] = (_Float16)x0.w;
      af[4] = (_Float16)x1.x; af[5] = (_Float16)x1.y;
      af[6] = (_Float16)x1.z; af[7] = (_Float16)x1.w;
#pragma unroll
      for (int nt = 0; nt < 4; ++nt)
        acc[nt] = __builtin_amdgcn_mfma_f32_16x16x32_f16(af, bf[nt * 4 + kk], acc[nt], 0, 0, 0);
    }
#pragma unroll
    for (int nt = 0; nt < 4; ++nt) {
#pragma unroll
      for (int r = 0; r < 4; ++r) {
        float val = acc[nt][r];
        float vd = val * a1d_l[nt];
        vd += __shfl_xor(vd, 1); vd += __shfl_xor(vd, 2); vd += __shfl_xor(vd, 4);
        int node = n0 + q * 4 + r;
        if (node < NN) {
          P1[((size_t)node << 6) + nt * 16 + c] = to_fp8(val);
          if ((c & 7) == 0) ed1[node * 8 + 2 * nt + (c >> 3)] = vd;
        }
      }
    }
  }
}

// ---------------- CSR phase-2: per-bucket histogram+scan+scatter (bscan folded in) ----------------

__global__ __launch_bounds__(256) void k_p2(const int* __restrict__ bcount,
                                            const int* __restrict__ bbuf,
                                            int* __restrict__ offsets,
                                            int* __restrict__ edge_src) {
  __shared__ int cnt[BKW];
  __shared__ int s1[BKW];
  __shared__ int cur[BKW];
  __shared__ int red[256];
  int b = blockIdx.x, tid = threadIdx.x;
  // inline exclusive prefix over buckets j < b of (bcount[j] + self-loops(j))
  int partial = 0;
  for (int j = tid; j < b; j += 256)
    partial += bcount[j] + min(BKW, NN - (j << 7));
  red[tid] = partial;
  __syncthreads();
  for (int off = 128; off >= 1; off >>= 1) {
    if (tid < off) red[tid] += red[tid + off];
    __syncthreads();
  }
  int base = red[0];
  int d0 = b << 7;
  int width = min(BKW, NN - d0);
  int n = bcount[b];
  const int* buf = bbuf + (size_t)b * BCAP;
  if (tid < BKW) cnt[tid] = (tid < width) ? 1 : 0;
  __syncthreads();
  for (int i = tid; i < n; i += 256) atomicAdd(&cnt[buf[i] & 127], 1);
  __syncthreads();
  if (tid < BKW) s1[tid] = cnt[tid];
  __syncthreads();
  for (int off = 1; off < BKW; off <<= 1) {
    int u = (tid < BKW && tid >= off) ? s1[tid - off] : 0;
    __syncthreads();
    if (tid < BKW) s1[tid] += u;
    __syncthreads();
  }
  if (tid < width) {
    int excl = s1[tid] - cnt[tid];
    offsets[d0 + tid] = base + excl;
    edge_src[base + excl] = d0 + tid;   // self-loop first
    cur[tid] = excl + 1;
  }
  if (b == 0 && tid == 0) offsets[NN] = ET;
  __syncthreads();
  for (int i = tid; i < n; i += 256) {
    int p = buf[i];
    int pos = atomicAdd(&cur[p & 127], 1);
    edge_src[base + pos] = p >> 7;
  }
}

// ---------------- Layer 1 aggregation: 8 dsts/wave, es recomputed, unroll 8 ----------------

__global__ __launch_bounds__(256) void k_agg1(
    const int* __restrict__ offsets, const int* __restrict__ edge_src,
    const unsigned char* __restrict__ P1, const float* __restrict__ a1s,
    const float* __restrict__ ed1, __half* __restrict__ x2) {
  int wv = threadIdx.x >> 6, lane = threadIdx.x & 63;
  int g = lane >> 3, p = lane & 7;        // group g: dst; lane p: head p, feats 8p..8p+7
  int dst = blockIdx.x * 32 + wv * 8 + g;
  float edv = ed1[dst * 8 + p];
  float4 as0 = *reinterpret_cast<const float4*>(a1s + p * 8);
  float4 as1 = *reinterpret_cast<const float4*>(a1s + p * 8 + 4);
  int beg = offsets[dst], end = offsets[dst + 1];
  int deg = end - beg;                    // >= 1 (self-loop)
  int md = deg;
#pragma unroll
  for (int o = 8; o < 64; o <<= 1) md = max(md, __shfl_xor(md, o, 64));
  float l = 0.f;
  float a[8] = {0.f, 0.f, 0.f, 0.f, 0.f, 0.f, 0.f, 0.f};
  for (int t = 0; t < md; t += 8) {
    int src[8]; uint2 raw[8];
#pragma unroll
    for (int i = 0; i < 8; ++i) {
      int idx = t + i;
      int ci = beg + ((idx < deg) ? idx : (deg - 1));
      src[i] = edge_src[ci];
    }
#pragma unroll
    for (int i = 0; i < 8; ++i)
      raw[i] = *reinterpret_cast<const uint2*>(P1 + ((size_t)src[i] << 6) + (p << 3));
#pragma unroll
    for (int i = 0; i < 8; ++i) {
      v2f f01 = __builtin_amdgcn_cvt_pk_f32_fp8(raw[i].x, false);
      v2f f23 = __builtin_amdgcn_cvt_pk_f32_fp8(raw[i].x, true);
      v2f f45 = __builtin_amdgcn_cvt_pk_f32_fp8(raw[i].y, false);
      v2f f67 = __builtin_amdgcn_cvt_pk_f32_fp8(raw[i].y, true);
      // recompute e_src for head p from the fp8 fragment
      float es = f01.x * as0.x + f01.y * as0.y + f23.x * as0.z + f23.y * as0.w
               + f45.x * as1.x + f45.y * as1.y + f67.x * as1.z + f67.y * as1.w;
      float e = lrelu(es + edv);
      float pr = (t + i < deg) ? __expf(e) : 0.f;   // |e|<3 provably: no max-shift
      l += pr;
      a[0] += pr * f01.x; a[1] += pr * f01.y;
      a[2] += pr * f23.x; a[3] += pr * f23.y;
      a[4] += pr * f45.x; a[5] += pr * f45.y;
      a[6] += pr * f67.x; a[7] += pr * f67.y;
    }
  }
  float rl = 1.f / l;
  union { __half h[8]; uint4 u; } pk;
#pragma unroll
  for (int i = 0; i < 8; ++i) {
    float v = a[i] * rl;
    v = (v > 0.f) ? v : (__expf(v) - 1.f);   // ELU fused
    pk.h[i] = __float2half(v);
  }
  *reinterpret_cast<uint4*>(x2 + ((size_t)dst << 6) + (p << 3)) = pk.u;
}

// ---------------- Layer 2: MFMA h2 = x2 @ W2 -> 64 B records (h fp8 @0..39, es fp16 @40) ----------------

__global__ __launch_bounds__(256) void k_gemm2(
    const __half* __restrict__ x2, const float* __restrict__ W2,
    const float* __restrict__ a2s, const float* __restrict__ a2d,
    unsigned char* __restrict__ P2, float* __restrict__ ed2) {
  __shared__ _Float16 Wb[6 * 64 * 8];   // 6 KB
  int tid = threadIdx.x;
  for (int idx = tid; idx < 6 * 64; idx += 256) {
    int f = idx >> 6, l = idx & 63;
    int nt = f >> 1, kk = f & 1;
    int ql = l >> 4, cl = l & 15;
    int col = nt * 16 + cl;
    int k0 = kk * 32 + ql * 8;
    v8h tmp;
#pragma unroll
    for (int j = 0; j < 8; ++j)
      tmp[j] = (col < 40) ? (_Float16)W2[(k0 + j) * 40 + col] : (_Float16)0.f;
    *reinterpret_cast<v8h*>(&Wb[idx * 8]) = tmp;
  }
  __syncthreads();
  int wv = tid >> 6, lane = tid & 63;
  int q = lane >> 4, c = lane & 15;
  v8h bf[6];
#pragma unroll
  for (int f = 0; f < 6; ++f)
    bf[f] = *reinterpret_cast<const v8h*>(&Wb[(f * 64 + lane) * 8]);
  float a2s_l[3], a2d_l[3];
#pragma unroll
  for (int nt = 0; nt < 3; ++nt) {
    int n = nt * 16 + c;
    a2s_l[nt] = (n < 40) ? a2s[n] : 0.f;
    a2d_l[nt] = (n < 40) ? a2d[n] : 0.f;
  }
  for (int t = 0; t < 4; ++t) {
    int n0 = blockIdx.x * 256 + wv * 64 + t * 16;
    int row = n0 + c;
    row = (row < NN) ? row : (NN - 1);
    v4f acc[3] = {{0.f,0.f,0.f,0.f},{0.f,0.f,0.f,0.f},{0.f,0.f,0.f,0.f}};
#pragma unroll
    for (int kk = 0; kk < 2; ++kk) {
      v8h af = *reinterpret_cast<const v8h*>(x2 + (size_t)row * 64 + kk * 32 + q * 8);
#pragma unroll
      for (int nt = 0; nt < 3; ++nt)
        acc[nt] = __builtin_amdgcn_mfma_f32_16x16x32_f16(af, bf[nt * 2 + kk], acc[nt], 0, 0, 0);
    }
#pragma unroll
    for (int r = 0; r < 4; ++r) {
      float v0 = acc[0][r], v1 = acc[1][r], v2 = acc[2][r];
      float s = v0 * a2s_l[0] + v1 * a2s_l[1] + v2 * a2s_l[2];
      float d = v0 * a2d_l[0] + v1 * a2d_l[1] + v2 * a2d_l[2];
      s += __shfl_xor(s, 1); s += __shfl_xor(s, 2); s += __shfl_xor(s, 4); s += __shfl_xor(s, 8);
      d += __shfl_xor(d, 1); d += __shfl_xor(d, 2); d += __shfl_xor(d, 4); d += __shfl_xor(d, 8);
      int node = n0 + q * 4 + r;
      if (node < NN) {
        unsigned char* rec = P2 + ((size_t)node << 6);
        if (c < 8) rec[32 + c] = to_fp8(v2);          // nt=2: classes 32..39
        rec[c]      = to_fp8(v0);                     // nt=0: classes 0..15
        rec[16 + c] = to_fp8(v1);                     // nt=1: classes 16..31
        if (c == 0) {
          *reinterpret_cast<__half*>(rec + 40) = __float2half(s);
          ed2[node] = d;
        }
      }
    }
  }
}

// ---------------- Layer 2 aggregation + log_softmax: 4 dsts/wave x 16 lanes ----------------
// exp-dedup: lane p&7 computes pr for edge p&7, broadcast via shuffle.

__global__ __launch_bounds__(256) void k_agg2(
    const int* __restrict__ offsets, const int* __restrict__ edge_src,
    const unsigned char* __restrict__ P2, const float* __restrict__ ed2,
    float* __restrict__ out) {
  int wv = threadIdx.x >> 6, lane = threadIdx.x & 63;
  int g = lane >> 4, p = lane & 15;   // lane p: classes 4p..4p+3; active p<10
  bool act = p < 10;
  int cp = act ? p : 0;
  int dst = blockIdx.x * 16 + wv * 4 + g;
  float edv = ed2[dst];
  int beg = offsets[dst], end = offsets[dst + 1];
  int deg = end - beg;
  int md = deg;
#pragma unroll
  for (int o = 16; o < 64; o <<= 1) md = max(md, __shfl_xor(md, o, 64));
  int gbase = lane & 48;              // first lane of this group
  int me = p & 7;                     // the edge this lane computes exp for
  float l = 0.f;
  float a[4] = {0.f, 0.f, 0.f, 0.f};
  for (int t = 0; t < md; t += 8) {
    int src[8]; unsigned raw[8];
#pragma unroll
    for (int i = 0; i < 8; ++i) {
      int ix = t + i;
      int ci = beg + ((ix < deg) ? ix : (deg - 1));
      src[i] = edge_src[ci];
    }
    // one es-load + one exp chain per lane, covering edge (p&7) of this group
    float myes = __half2float(*reinterpret_cast<const __half*>(
        P2 + ((size_t)src[me] << 6) + 40));
    float mye = lrelu(myes + edv);
    float mypr = (t + me < deg) ? __expf(mye) : 0.f;
#pragma unroll
    for (int i = 0; i < 8; ++i)
      raw[i] = *reinterpret_cast<const unsigned*>(P2 + ((size_t)src[i] << 6) + (cp << 2));
#pragma unroll
    for (int i = 0; i < 8; ++i) {
      float pr = __shfl(mypr, gbase | i, 64);
      v2f f01 = __builtin_amdgcn_cvt_pk_f32_fp8(raw[i], false);
      v2f f23 = __builtin_amdgcn_cvt_pk_f32_fp8(raw[i], true);
      l += pr;
      a[0] += pr * f01.x; a[1] += pr * f01.y;
      a[2] += pr * f23.x; a[3] += pr * f23.y;
    }
  }
  float rl = 1.f / l;
  float v0 = a[0] * rl, v1 = a[1] * rl, v2 = a[2] * rl, v3 = a[3] * rl;
  float red = act ? fmaxf(fmaxf(v0, v1), fmaxf(v2, v3)) : -INFINITY;
#pragma unroll
  for (int o = 1; o < 16; o <<= 1) red = fmaxf(red, __shfl_xor(red, o, 64));
  float se = act ? (__expf(v0 - red) + __expf(v1 - red) + __expf(v2 - red) + __expf(v3 - red)) : 0.f;
#pragma unroll
  for (int o = 1; o < 16; o <<= 1) se += __shfl_xor(se, o, 64);
  float ls = red + __logf(se);
  if (act) {
    float4 o4 = make_float4(v0 - ls, v1 - ls, v2 - ls, v3 - ls);
    *reinterpret_cast<float4*>(out + (size_t)dst * 40 + (p << 2)) = o4;
  }
}

// ---------------- launch ----------------

extern "C" void kernel_launch(void* const* d_in, const int* in_sizes, int n_in,
                              void* d_out, int out_size, void* d_ws, size_t ws_size,
                              hipStream_t stream) {
  const float* x   = (const float*)d_in[0];
  const int*   adj = (const int*)d_in[1];     // [2, EE]
  const float* W1  = (const float*)d_in[2];
  const float* a1s = (const float*)d_in[3];
  const float* a1d = (const float*)d_in[4];
  const float* W2  = (const float*)d_in[5];
  const float* a2s = (const float*)d_in[6];
  const float* a2d = (const float*)d_in[7];
  float* out = (float*)d_out;

  const int* srcs = adj;
  const int* dsts = adj + EE;

  char* w = (char*)d_ws;
  size_t off = 0;
  auto alloc = [&](size_t bytes) -> void* {
    void* p = w + off;
    off = (off + bytes + 255) & ~(size_t)255;
    return p;
  };
  int* offsets      = (int*)alloc((size_t)(NN + 1) * 4);
  int* edge_src     = (int*)alloc((size_t)ET * 4);
  int* bcount       = (int*)alloc((size_t)NBK * 4);
  unsigned char* P1 = (unsigned char*)alloc((size_t)NN * 64);  // 6.4 MB fp8 h, 64 B/line recs
  float* ed1        = (float*)alloc((size_t)NN * 8 * 4);       // 3.2 MB
  __half* x2        = (__half*)alloc((size_t)NN * 64 * 2);     // 12.8 MB
  int* bbuf         = (int*)alloc((size_t)NBK * BCAP * 4);     // 16 MB
  // layer-2 buffers alias layer-1 (P1/ed1 dead after k_agg1):
  unsigned char* P2 = P1;     // 6.4 MB == 6.4 MB
  float* ed2 = ed1;

  hipMemsetAsync(bcount, 0, (size_t)NBK * 4, stream);
  k_p1g1<<<NB_P1 + NB_G, 256, 0, stream>>>(srcs, dsts, bcount, bbuf,
                                           x, W1, a1d, P1, ed1);
  k_p2<<<NBK, 256, 0, stream>>>(bcount, bbuf, offsets, edge_src);

  k_agg1<<<NN / 32, 256, 0, stream>>>(offsets, edge_src, P1, a1s, ed1, x2);
  k_gemm2<<<NB_G, 256, 0, stream>>>(x2, W2, a2s, a2d, P2, ed2);
  k_agg2<<<NN / 16, 256, 0, stream>>>(offsets, edge_src, P2, ed2, out);
}